// Round 3
// baseline (597.495 us; speedup 1.0000x reference)
//
#include <hip/hip_runtime.h>
#include <hip/hip_cooperative_groups.h>

namespace cg = cooperative_groups;

// MultiHeadedTrilinearAttention, MI355X — round 8.
// Post-mortem r6/r7: per-iteration caches are cold (256MiB poison fill each
// iter), so the byte-minimal round-5 dataflow (transpose/convert weights ONCE,
// read compact f16) beats any scheme that re-reads f32 W per tile. Regressions
// (+6/+11us) matched the added 27-60MB logical traffic.
// Round 8: keep round-5 dataflow EXACTLY, remove the 3 kernel boundaries via a
// single cooperative launch with grid.sync() between phases.
//   P0 prep (1008 units) -> P1 proj1 (1152 wave-tiles) -> P2 proj2 -> P3 fused
// Fallback to the plain 4-kernel chain if cooperative launch is refused.
// ws layout: Wt f16 [6][768][768] | vI,qI,aI f16 | vpH,qpH,apH f16 | vo,qo,ao f32.

#define DIM   768
#define SEQ   128
#define NH    12
#define HW    64
#define PROJ_ELEMS (SEQ * DIM)   // 98304
#define WELEMS     (DIM * DIM)   // 589824
#define QOUT_OFF   98304
#define AOUT_OFF   196608
#define NBLK  768                // cooperative grid size (3 blocks/CU x 256 CU)

typedef _Float16 f16x8 __attribute__((ext_vector_type(8)));
typedef float    f32x4 __attribute__((ext_vector_type(4)));

// ---------------- device helpers (shared by coop + fallback paths) ---------

// 64x64 transpose+convert tile of W into WtM ([n][k] f16). 256 threads.
__device__ __forceinline__ void prep_weight_tile(
    const float* __restrict__ W, _Float16* __restrict__ WtM,
    int k0, int n0, int t, _Float16 (*T)[72])
{
    const int c4 = (t & 15) * 4;
    #pragma unroll
    for (int p = 0; p < 4; ++p) {
        const int r = (t >> 4) + 16 * p;     // k-local
        f32x4 wv = *(const f32x4*)&W[(k0 + r) * DIM + n0 + c4];
        T[c4 + 0][r] = (_Float16)wv[0];
        T[c4 + 1][r] = (_Float16)wv[1];
        T[c4 + 2][r] = (_Float16)wv[2];
        T[c4 + 3][r] = (_Float16)wv[3];
    }
    __syncthreads();
    const int c2 = (t & 7) * 8;
    #pragma unroll
    for (int p = 0; p < 2; ++p) {
        const int r = (t >> 3) + 32 * p;     // n-local
        *(f16x8*)&WtM[(n0 + r) * DIM + k0 + c2] = *(const f16x8*)&T[r][c2];
    }
}

// convert 2048 f32 -> f16 at offset, 256 threads x 8 elems
__device__ __forceinline__ void convert_unit(
    const float* __restrict__ src, _Float16* __restrict__ dst, int off)
{
    f32x4 lo = *(const f32x4*)&src[off];
    f32x4 hi = *(const f32x4*)&src[off + 4];
    f16x8 o;
    o[0] = (_Float16)lo[0]; o[1] = (_Float16)lo[1];
    o[2] = (_Float16)lo[2]; o[3] = (_Float16)lo[3];
    o[4] = (_Float16)hi[0]; o[5] = (_Float16)hi[1];
    o[6] = (_Float16)hi[2]; o[7] = (_Float16)hi[3];
    *(f16x8*)&dst[off] = o;
}

// 1-wave 16x16 GEMM tile: C[m0:+16, n0:+16] = A@T^T + b. A,T f16; LDS-free.
template <int OUT16>
__device__ __forceinline__ void proj_tile(
    const _Float16* __restrict__ A, const _Float16* __restrict__ T,
    const float* __restrict__ bb, void* __restrict__ C,
    int m0, int n0, int lane)
{
    const int fm = lane & 15;
    const int fk = (lane >> 4) << 3;
    const _Float16* pa = A + (m0 + fm) * DIM + fk;
    const _Float16* pb = T + (n0 + fm) * DIM + fk;
    f32x4 acc = (f32x4){0.f, 0.f, 0.f, 0.f};
    #pragma unroll
    for (int s = 0; s < 24; ++s) {
        const f16x8 af = *(const f16x8*)(pa + 32 * s);
        const f16x8 wf = *(const f16x8*)(pb + 32 * s);
        acc = __builtin_amdgcn_mfma_f32_16x16x32_f16(af, wf, acc, 0, 0, 0);
    }
    const int col  = n0 + fm;
    const int row0 = m0 + ((lane >> 4) << 2);
    const float bi = bb[col];
    #pragma unroll
    for (int rr = 0; rr < 4; ++rr) {
        const float val = acc[rr] + bi;
        if (OUT16) ((_Float16*)C)[(row0 + rr) * DIM + col] = (_Float16)val;
        else       ((float*)C)[(row0 + rr) * DIM + col]    = val;
    }
}

// fused trilinear scores + group softmax + marginal outputs for one (vtok,h).
// 256 threads; smem = 2 x [128][72] f16 (36864B). Validated round-4/5 logic.
__device__ __forceinline__ void fused_unit(
    int vtok, int h, int t, char* smem,
    const _Float16* __restrict__ vpH, const _Float16* __restrict__ qpH,
    const _Float16* __restrict__ apH,
    const float* __restrict__ vo, const float* __restrict__ qo,
    const float* __restrict__ ao, float* __restrict__ out)
{
    _Float16 (*vqL)[72] = (_Float16(*)[72])smem;                  // [q][k]
    _Float16 (*ahL)[72] = (_Float16(*)[72])(smem + 128 * 72 * 2); // [a][k]

    const int w    = t >> 6;
    const int lane = t & 63;
    const int fm   = lane & 15;
    const int fk   = (lane >> 4) << 3;

    {
        const int r  = t >> 1;
        const int kh = (t & 1) << 5;
        const _Float16* pq = qpH + r    * DIM + h * HW + kh;
        const _Float16* pv = vpH + vtok * DIM + h * HW + kh;
        const _Float16* pa = apH + r    * DIM + h * HW + kh;
        #pragma unroll
        for (int u = 0; u < 4; ++u) {
            const f16x8 qv = *(const f16x8*)(pq + 8 * u);
            const f16x8 vv = *(const f16x8*)(pv + 8 * u);
            const f16x8 av = *(const f16x8*)(pa + 8 * u);
            *(f16x8*)&vqL[r][kh + 8 * u] = qv * vv;   // v_pk_mul_f16
            *(f16x8*)&ahL[r][kh + 8 * u] = av;
        }
    }
    __syncthreads();

    f32x4 acc[2][8];
    #pragma unroll
    for (int qt = 0; qt < 2; ++qt)
        #pragma unroll
        for (int at = 0; at < 8; ++at)
            acc[qt][at] = (f32x4){0.f, 0.f, 0.f, 0.f};

    const int q0 = 32 * w;
    #pragma unroll
    for (int ks = 0; ks < 2; ++ks) {
        const f16x8 af0 = *(const f16x8*)&vqL[q0 + fm     ][32 * ks + fk];
        const f16x8 af1 = *(const f16x8*)&vqL[q0 + 16 + fm][32 * ks + fk];
        #pragma unroll
        for (int at = 0; at < 8; ++at) {
            const f16x8 bf = *(const f16x8*)&ahL[16 * at + fm][32 * ks + fk];
            acc[0][at] = __builtin_amdgcn_mfma_f32_16x16x32_f16(af0, bf, acc[0][at], 0, 0, 0);
            acc[1][at] = __builtin_amdgcn_mfma_f32_16x16x32_f16(af1, bf, acc[1][at], 0, 0, 0);
        }
    }

    float sv[2][2] = {{0.f, 0.f}, {0.f, 0.f}};
    float sq[2][8];
    #pragma unroll
    for (int i = 0; i < 2; ++i)
        #pragma unroll
        for (int j = 0; j < 8; ++j) sq[i][j] = 0.f;
    float sa = 0.f;
    #pragma unroll
    for (int qt = 0; qt < 2; ++qt)
        #pragma unroll
        for (int at = 0; at < 8; ++at)
            #pragma unroll
            for (int rr = 0; rr < 4; ++rr) {
                const float e = __expf(acc[qt][at][rr] * 0.125f);
                sv[qt][rr >> 1] += e;
                sq[rr & 1][at]  += e;
                sa += e;
            }

    sa += __shfl_xor(sa, 16);
    sa += __shfl_xor(sa, 32);
    float tot = sa;
    tot += __shfl_xor(tot, 1);
    tot += __shfl_xor(tot, 2);
    tot += __shfl_xor(tot, 4);
    tot += __shfl_xor(tot, 8);
    const bool b0 = lane & 1;
    const bool b1 = lane & 2;
    float sF;
    {
        float snd0 = b0 ? sv[0][0] : sv[1][0];
        float snd1 = b0 ? sv[0][1] : sv[1][1];
        float r0 = __shfl_xor(snd0, 1);
        float r1 = __shfl_xor(snd1, 1);
        float s0 = (b0 ? sv[1][0] : sv[0][0]) + r0;   // qt = b0, rh = 0
        float s1 = (b0 ? sv[1][1] : sv[0][1]) + r1;   // qt = b0, rh = 1
        float snd = b1 ? s0 : s1;
        float r2 = __shfl_xor(snd, 2);
        sF = (b1 ? s1 : s0) + r2;                     // qt = b0, rh = b1
    }
    sF += __shfl_xor(sF, 4);
    sF += __shfl_xor(sF, 8);
    float s[16];
    #pragma unroll
    for (int i = 0; i < 2; ++i)
        #pragma unroll
        for (int j = 0; j < 8; ++j) s[i * 8 + j] = sq[i][j];
    #pragma unroll
    for (int k = 0; k < 4; ++k) {
        const int d = 1 << k;
        const int m = 16 >> (k + 1);
        const bool b = (lane >> k) & 1;
        #pragma unroll
        for (int x = 0; x < m; ++x) {
            const float snd = b ? s[x] : s[x + m];
            const float rcv = __shfl_xor(snd, d);
            s[x] = (b ? s[x + m] : s[x]) + rcv;
        }
    }
    s[0] += __shfl_xor(s[0], 16);
    s[0] += __shfl_xor(s[0], 32);

    const int g  = h * 512 + vtok * 4 + w;    // softmax group id
    const int b2 = g / 12;
    const int h2 = g - b2 * 12;
    const float invZ = 1.0f / tot;
    const int obase = vtok * DIM + h * HW + w * 16;

    if (fm < 4) {                             // v-outputs
        const int quad = lane >> 4;
        const int bin  = (fm & 1) * 8 + quad * 2 + ((fm >> 1) & 1);
        out[(b2 * 16 + bin) * 12 + h2] = sF * invZ * vo[obase + bin];
    }
    if (lane < 16) {                          // q- and a-outputs
        const int qbin = 8 * (lane & 1) + 4 * ((lane >> 1) & 1)
                       + 2 * ((lane >> 2) & 1) + (lane >> 3);
        out[QOUT_OFF + (b2 * 16 + qbin) * 12 + h2] = s[0] * invZ * qo[obase + qbin];
        out[AOUT_OFF + (b2 * 16 + lane) * 12 + h2] = sa   * invZ * ao[obase + lane];
    }
}

// ---------------- cooperative mega-kernel: all 4 phases, 1 launch ----------
__global__ __launch_bounds__(256, 3) void mega_kernel(
    const float* __restrict__ v, const float* __restrict__ q, const float* __restrict__ a,
    const float* __restrict__ Wv, const float* __restrict__ bv,
    const float* __restrict__ Wq, const float* __restrict__ bq,
    const float* __restrict__ Wa, const float* __restrict__ ba,
    const float* __restrict__ Wvo, const float* __restrict__ bvo,
    const float* __restrict__ Wqo, const float* __restrict__ bqo,
    const float* __restrict__ Wao, const float* __restrict__ bao,
    _Float16* __restrict__ Wt,
    _Float16* __restrict__ vI, _Float16* __restrict__ qI, _Float16* __restrict__ aI,
    _Float16* __restrict__ vpH, _Float16* __restrict__ qpH, _Float16* __restrict__ apH,
    float* __restrict__ vo, float* __restrict__ qo, float* __restrict__ ao,
    float* __restrict__ out)
{
    cg::grid_group grid = cg::this_grid();
    __shared__ __align__(16) char smem[2 * 128 * 72 * 2];   // 36864 B
    const int t = threadIdx.x;

    // ---- P0: weight transpose+convert (864 units) + input convert (144) ----
    for (int u = blockIdx.x; u < 1008; u += NBLK) {
        if (u < 864) {
            const int mat  = u / 144;
            const int tile = u - mat * 144;
            const int kx = tile % 12;
            const int ny = tile / 12;
            const float* W = (mat == 0) ? Wv : (mat == 1) ? Wq : (mat == 2) ? Wa
                           : (mat == 3) ? Wvo : (mat == 4) ? Wqo : Wao;
            prep_weight_tile(W, Wt + mat * WELEMS, kx * 64, ny * 64, t,
                             (_Float16(*)[72])smem);
            __syncthreads();   // smem reuse across u-loop iterations
        } else {
            const int bid = u - 864;                 // 0..143
            const int mat = bid / 48;
            const int off = (bid - mat * 48) * 2048 + t * 8;
            const float* src = (mat == 0) ? v : (mat == 1) ? q : a;
            _Float16* dst    = (mat == 0) ? vI : (mat == 1) ? qI : aI;
            convert_unit(src, dst, off);
        }
    }
    __threadfence();
    grid.sync();

    // ---- P1: stage-1 projections (1152 one-wave tiles, f16 out) ----
    {
        const int wg = blockIdx.x * 4 + (t >> 6);
        if (wg < 1152) {
            const int mat = wg / 384;
            const int rem = wg - mat * 384;
            const int m0 = (rem & 7) * 16;
            const int n0 = (rem >> 3) * 16;
            const _Float16* A = (mat == 0) ? vI : (mat == 1) ? qI : aI;
            const float* bb   = (mat == 0) ? bv : (mat == 1) ? bq : ba;
            _Float16* C       = (mat == 0) ? vpH : (mat == 1) ? qpH : apH;
            proj_tile<1>(A, Wt + mat * WELEMS, bb, C, m0, n0, t & 63);
        }
    }
    __threadfence();
    grid.sync();

    // ---- P2: stage-2 projections (1152 one-wave tiles, f32 out) ----
    {
        const int wg = blockIdx.x * 4 + (t >> 6);
        if (wg < 1152) {
            const int mat = wg / 384;
            const int rem = wg - mat * 384;
            const int m0 = (rem & 7) * 16;
            const int n0 = (rem >> 3) * 16;
            const _Float16* A = (mat == 0) ? vpH : (mat == 1) ? qpH : apH;
            const float* bb   = (mat == 0) ? bvo : (mat == 1) ? bqo : bao;
            float* C          = (mat == 0) ? vo : (mat == 1) ? qo : ao;
            proj_tile<0>(A, Wt + (3 + mat) * WELEMS, bb, C, m0, n0, t & 63);
        }
    }
    __threadfence();
    grid.sync();

    // ---- P3: fused attention (1536 units, 2 per block) ----
    #pragma unroll
    for (int r = 0; r < 2; ++r) {
        const int unit = blockIdx.x + r * NBLK;   // < 1536
        const int vtok = unit & 127;
        const int h    = unit >> 7;
        __syncthreads();   // protect smem reuse vs previous iteration's reads
        fused_unit(vtok, h, t, smem, vpH, qpH, apH, vo, qo, ao, out);
    }
}

// ---------------- fallback: plain 4-kernel chain (round-5 structure) -------
__global__ __launch_bounds__(256) void prep_kernel(
    const float* __restrict__ v, const float* __restrict__ q, const float* __restrict__ a,
    const float* __restrict__ W0, const float* __restrict__ W1, const float* __restrict__ W2,
    const float* __restrict__ W3, const float* __restrict__ W4, const float* __restrict__ W5,
    _Float16* __restrict__ Wt,
    _Float16* __restrict__ vI, _Float16* __restrict__ qI, _Float16* __restrict__ aI)
{
    const int z = blockIdx.z;
    const int t = threadIdx.x;
    __shared__ __align__(16) _Float16 T[64][72];
    if (z < 6) {
        const float* W = (z == 0) ? W0 : (z == 1) ? W1 : (z == 2) ? W2
                       : (z == 3) ? W3 : (z == 4) ? W4 : W5;
        prep_weight_tile(W, Wt + z * WELEMS, blockIdx.x * 64, blockIdx.y * 64, t, T);
    } else {
        const int bid = blockIdx.x + 12 * blockIdx.y;  // 0..143
        const int mat = bid / 48;
        const int off = (bid - mat * 48) * 2048 + t * 8;
        const float* src = (mat == 0) ? v : (mat == 1) ? q : a;
        _Float16* dst    = (mat == 0) ? vI : (mat == 1) ? qI : aI;
        convert_unit(src, dst, off);
    }
}

template <int OUT16>
__global__ __launch_bounds__(64) void proj_kernel(
    const _Float16* __restrict__ A0, const _Float16* __restrict__ A1, const _Float16* __restrict__ A2,
    const _Float16* __restrict__ T0, const _Float16* __restrict__ T1, const _Float16* __restrict__ T2,
    const float* __restrict__ b0, const float* __restrict__ b1, const float* __restrict__ b2,
    void* __restrict__ C0, void* __restrict__ C1, void* __restrict__ C2)
{
    const int mat = blockIdx.z;
    const _Float16* A = (mat == 0) ? A0 : (mat == 1) ? A1 : A2;
    const _Float16* T = (mat == 0) ? T0 : (mat == 1) ? T1 : T2;
    const float* bb   = (mat == 0) ? b0 : (mat == 1) ? b1 : b2;
    void* C           = (mat == 0) ? C0 : (mat == 1) ? C1 : C2;
    proj_tile<OUT16>(A, T, bb, C, blockIdx.x * 16, blockIdx.y * 16, threadIdx.x & 63);
}

__global__ __launch_bounds__(256) void fused_attn_kernel(
    const _Float16* __restrict__ vpH, const _Float16* __restrict__ qpH,
    const _Float16* __restrict__ apH,
    const float* __restrict__ vo, const float* __restrict__ qo, const float* __restrict__ ao,
    float* __restrict__ out)
{
    __shared__ __align__(16) char smem[2 * 128 * 72 * 2];
    fused_unit(blockIdx.x, blockIdx.y, threadIdx.x, smem, vpH, qpH, apH, vo, qo, ao, out);
}

extern "C" void kernel_launch(void* const* d_in, const int* in_sizes, int n_in,
                              void* d_out, int out_size, void* d_ws, size_t ws_size,
                              hipStream_t stream)
{
    const float* v   = (const float*)d_in[0];
    const float* q   = (const float*)d_in[1];
    const float* a   = (const float*)d_in[2];
    // d_in[3..5] = masks, unused by the reference forward
    const float* Wv  = (const float*)d_in[6];
    const float* bv  = (const float*)d_in[7];
    const float* Wq  = (const float*)d_in[8];
    const float* bq  = (const float*)d_in[9];
    const float* Wa  = (const float*)d_in[10];
    const float* ba  = (const float*)d_in[11];
    const float* Wvo = (const float*)d_in[12];
    const float* bvo = (const float*)d_in[13];
    const float* Wqo = (const float*)d_in[14];
    const float* bqo = (const float*)d_in[15];
    const float* Wao = (const float*)d_in[16];
    const float* bao = (const float*)d_in[17];

    float* out = (float*)d_out;

    _Float16* Wt  = (_Float16*)d_ws;             // 6 * 589824 f16
    _Float16* vI  = Wt + 6 * WELEMS;
    _Float16* qI  = vI + PROJ_ELEMS;
    _Float16* aI  = qI + PROJ_ELEMS;
    _Float16* vpH = aI + PROJ_ELEMS;
    _Float16* qpH = vpH + PROJ_ELEMS;
    _Float16* apH = qpH + PROJ_ELEMS;
    float*    vo  = (float*)(apH + PROJ_ELEMS);
    float*    qo  = vo + PROJ_ELEMS;
    float*    ao  = qo + PROJ_ELEMS;

    void* args[] = {
        (void*)&v, (void*)&q, (void*)&a,
        (void*)&Wv, (void*)&bv, (void*)&Wq, (void*)&bq, (void*)&Wa, (void*)&ba,
        (void*)&Wvo, (void*)&bvo, (void*)&Wqo, (void*)&bqo, (void*)&Wao, (void*)&bao,
        (void*)&Wt, (void*)&vI, (void*)&qI, (void*)&aI,
        (void*)&vpH, (void*)&qpH, (void*)&apH,
        (void*)&vo, (void*)&qo, (void*)&ao,
        (void*)&out
    };
    hipError_t err = hipLaunchCooperativeKernel(
        (const void*)mega_kernel, dim3(NBLK), dim3(256), args, 0, stream);

    if (err != hipSuccess) {
        // fallback: verified round-5 4-kernel chain (same device code)
        prep_kernel<<<dim3(12, 12, 7), 256, 0, stream>>>(
            v, q, a, Wv, Wq, Wa, Wvo, Wqo, Wao, Wt, vI, qI, aI);
        proj_kernel<1><<<dim3(8, 48, 3), 64, 0, stream>>>(
            vI, qI, aI, Wt, Wt + WELEMS, Wt + 2 * WELEMS,
            bv, bq, ba, vpH, qpH, apH);
        proj_kernel<0><<<dim3(8, 48, 3), 64, 0, stream>>>(
            vpH, qpH, apH, Wt + 3 * WELEMS, Wt + 4 * WELEMS, Wt + 5 * WELEMS,
            bvo, bqo, bao, vo, qo, ao);
        fused_attn_kernel<<<dim3(SEQ, NH), 256, 0, stream>>>(
            vpH, qpH, apH, vo, qo, ao, out);
    }
}

// Round 4
// 139.269 us; speedup vs baseline: 4.2902x; 4.2902x over previous
//
#include <hip/hip_runtime.h>

// MultiHeadedTrilinearAttention, MI355X — round 9 = verified round-5 revert.
// Ledger: r6 (3-launch, strided W) +6us; r7 (3-launch, LDS-restaged W) +11us;
// r8 (cooperative mega-kernel) +460us (grid.sync is a global atomic barrier —
// MfmaUtil 0.3%, idle-dominated). The r5 dataflow is byte-minimal under the
// harness's per-iteration cold caches (256MiB poison fill each iter): weights
// transposed+converted ONCE, all subsequent reads compact f16. Launch-gap
// capture attempts all cost more than the ~9us they target.
// ws layout: Wt f16 [6][768][768] | vI,qI,aI f16 | vpH,qpH,apH f16 | vo,qo,ao f32.

#define DIM   768
#define SEQ   128
#define NH    12
#define HW    64
#define PROJ_ELEMS (SEQ * DIM)   // 98304
#define WELEMS     (DIM * DIM)   // 589824
#define QOUT_OFF   98304
#define AOUT_OFF   196608

typedef _Float16 f16x8 __attribute__((ext_vector_type(8)));
typedef float    f32x4 __attribute__((ext_vector_type(4)));

// ---------------- prep: transpose+convert weights, convert inputs ----------
// grid (12,12,7). z<6: 64x64 transpose tile of weight z into Wt[z] ([n][k] f16).
// z==6: convert v,q,a fp32 -> f16 row-major (144 blocks x 2048 elems).
__global__ __launch_bounds__(256) void prep_kernel(
    const float* __restrict__ v, const float* __restrict__ q, const float* __restrict__ a,
    const float* __restrict__ W0, const float* __restrict__ W1, const float* __restrict__ W2,
    const float* __restrict__ W3, const float* __restrict__ W4, const float* __restrict__ W5,
    _Float16* __restrict__ Wt,
    _Float16* __restrict__ vI, _Float16* __restrict__ qI, _Float16* __restrict__ aI)
{
    const int z = blockIdx.z;
    const int t = threadIdx.x;
    if (z < 6) {
        const float* W = (z == 0) ? W0 : (z == 1) ? W1 : (z == 2) ? W2
                       : (z == 3) ? W3 : (z == 4) ? W4 : W5;
        _Float16* WtM = Wt + z * WELEMS;
        __shared__ _Float16 T[64][72];
        const int k0 = blockIdx.x * 64;
        const int n0 = blockIdx.y * 64;
        const int c4 = (t & 15) * 4;
        #pragma unroll
        for (int p = 0; p < 4; ++p) {
            const int r = (t >> 4) + 16 * p;     // k-local
            f32x4 wv = *(const f32x4*)&W[(k0 + r) * DIM + n0 + c4];
            T[c4 + 0][r] = (_Float16)wv[0];
            T[c4 + 1][r] = (_Float16)wv[1];
            T[c4 + 2][r] = (_Float16)wv[2];
            T[c4 + 3][r] = (_Float16)wv[3];
        }
        __syncthreads();
        const int c2 = (t & 7) * 8;
        #pragma unroll
        for (int p = 0; p < 2; ++p) {
            const int r = (t >> 3) + 32 * p;     // n-local
            *(f16x8*)&WtM[(n0 + r) * DIM + k0 + c2] = *(const f16x8*)&T[r][c2];
        }
    } else {
        const int bid = blockIdx.x + 12 * blockIdx.y;  // 0..143
        const int mat = bid / 48;
        const int off = (bid - mat * 48) * 2048 + t * 8;
        const float* src = (mat == 0) ? v : (mat == 1) ? q : a;
        _Float16* dst    = (mat == 0) ? vI : (mat == 1) ? qI : aI;
        f32x4 lo = *(const f32x4*)&src[off];
        f32x4 hi = *(const f32x4*)&src[off + 4];
        f16x8 o;
        o[0] = (_Float16)lo[0]; o[1] = (_Float16)lo[1];
        o[2] = (_Float16)lo[2]; o[3] = (_Float16)lo[3];
        o[4] = (_Float16)hi[0]; o[5] = (_Float16)hi[1];
        o[6] = (_Float16)hi[2]; o[7] = (_Float16)hi[3];
        *(f16x8*)&dst[off] = o;
    }
}

// ---------------- projection GEMM: 1 wave = 16x16 tile, LDS-free -----------
// C[128,768] = A[128,768]@W + b. A f16 row-major, W pre-transposed f16 [n][k].
// grid (8 m-tiles, 48 n-tiles, 3 matrices), 64 threads. 48 independent 16B
// loads fully unrolled -> batched issue; 24 MFMA chain on acc.
__global__ __launch_bounds__(64) void proj_kernel(
    const _Float16* __restrict__ A0, const _Float16* __restrict__ A1, const _Float16* __restrict__ A2,
    const _Float16* __restrict__ T0, const _Float16* __restrict__ T1, const _Float16* __restrict__ T2,
    const float* __restrict__ b0, const float* __restrict__ b1, const float* __restrict__ b2,
    void* __restrict__ C0, void* __restrict__ C1, void* __restrict__ C2,
    int out_f16)
{
    const int mat = blockIdx.z;
    const _Float16* __restrict__ A = (mat == 0) ? A0 : (mat == 1) ? A1 : A2;
    const _Float16* __restrict__ T = (mat == 0) ? T0 : (mat == 1) ? T1 : T2;
    const float* __restrict__ bb   = (mat == 0) ? b0 : (mat == 1) ? b1 : b2;
    void* __restrict__ C           = (mat == 0) ? C0 : (mat == 1) ? C1 : C2;

    const int m0   = blockIdx.x * 16;
    const int n0   = blockIdx.y * 16;
    const int lane = threadIdx.x & 63;
    const int fm   = lane & 15;
    const int fk   = (lane >> 4) << 3;

    const _Float16* pa = A + (m0 + fm) * DIM + fk;
    const _Float16* pb = T + (n0 + fm) * DIM + fk;

    f32x4 acc = (f32x4){0.f, 0.f, 0.f, 0.f};
    #pragma unroll
    for (int s = 0; s < 24; ++s) {
        const f16x8 af = *(const f16x8*)(pa + 32 * s);
        const f16x8 wf = *(const f16x8*)(pb + 32 * s);
        acc = __builtin_amdgcn_mfma_f32_16x16x32_f16(af, wf, acc, 0, 0, 0);
    }

    const int col  = n0 + fm;
    const int row0 = m0 + ((lane >> 4) << 2);
    const float bi = bb[col];
    #pragma unroll
    for (int rr = 0; rr < 4; ++rr) {
        const float val = acc[rr] + bi;
        if (out_f16) ((_Float16*)C)[(row0 + rr) * DIM + col] = (_Float16)val;
        else         ((float*)C)[(row0 + rr) * DIM + col]    = val;
    }
}

// -------- fused MFMA scores + group softmax + marginals + outputs --------
// block = (v-token, head). S[q][a] = sum_k vq[q,k]*ah[a,k], f16 MFMA, both
// operands staged in LDS. wave w == softmax group (q in [32w,32w+32)).
// C layout: col a = at*16+fm; row q'' = qt*16 + quad*4 + rr. No max-sub
// (scores ~N(0,0.17) — exp safe). Epilogue gathers simplify to
// vo[vtok*DIM + h*64 + w*16 + bin] (contiguous).
__global__ __launch_bounds__(256) void fused_attn_kernel(
    const _Float16* __restrict__ vpH, const _Float16* __restrict__ qpH,
    const _Float16* __restrict__ apH,
    const float* __restrict__ vo, const float* __restrict__ qo, const float* __restrict__ ao,
    float* __restrict__ out)
{
    const int vtok = blockIdx.x;   // 0..127
    const int h    = blockIdx.y;   // 0..11

    __shared__ _Float16 vqL[128][72];  // [q][k] f16, pad 72
    __shared__ _Float16 ahL[128][72];  // [a][k] f16

    const int t    = threadIdx.x;
    const int w    = t >> 6;
    const int lane = t & 63;
    const int fm   = lane & 15;
    const int fk   = (lane >> 4) << 3;

    // staging: thread t -> row r = t>>1, k-half kh = (t&1)*32
    {
        const int r  = t >> 1;
        const int kh = (t & 1) << 5;
        const _Float16* pq = qpH + r    * DIM + h * HW + kh;
        const _Float16* pv = vpH + vtok * DIM + h * HW + kh;
        const _Float16* pa = apH + r    * DIM + h * HW + kh;
        #pragma unroll
        for (int u = 0; u < 4; ++u) {
            const f16x8 qv = *(const f16x8*)(pq + 8 * u);
            const f16x8 vv = *(const f16x8*)(pv + 8 * u);
            const f16x8 av = *(const f16x8*)(pa + 8 * u);
            *(f16x8*)&vqL[r][kh + 8 * u] = qv * vv;   // v_pk_mul_f16
            *(f16x8*)&ahL[r][kh + 8 * u] = av;
        }
    }
    __syncthreads();

    f32x4 acc[2][8];
    #pragma unroll
    for (int qt = 0; qt < 2; ++qt)
        #pragma unroll
        for (int at = 0; at < 8; ++at)
            acc[qt][at] = (f32x4){0.f, 0.f, 0.f, 0.f};

    const int q0 = 32 * w;
    #pragma unroll
    for (int ks = 0; ks < 2; ++ks) {
        const f16x8 af0 = *(const f16x8*)&vqL[q0 + fm     ][32 * ks + fk];
        const f16x8 af1 = *(const f16x8*)&vqL[q0 + 16 + fm][32 * ks + fk];
        #pragma unroll
        for (int at = 0; at < 8; ++at) {
            const f16x8 bf = *(const f16x8*)&ahL[16 * at + fm][32 * ks + fk];
            acc[0][at] = __builtin_amdgcn_mfma_f32_16x16x32_f16(af0, bf, acc[0][at], 0, 0, 0);
            acc[1][at] = __builtin_amdgcn_mfma_f32_16x16x32_f16(af1, bf, acc[1][at], 0, 0, 0);
        }
    }

    // exp + marginal partials (no max subtraction).
    // q'' = qt*16 + quad*4 + rr ; a = at*16 + fm
    // v-bin = q''>>1 = qt*8 + quad*2 + (rr>>1) -> sv[qt][rr>>1] (quad in lane)
    // q-bin = (rr&1)*8 + at                    -> sq[rr&1][at]  (lane-uniform)
    // a-bin = fm                               -> sa            (fm in lane)
    float sv[2][2] = {{0.f, 0.f}, {0.f, 0.f}};
    float sq[2][8];
    #pragma unroll
    for (int i = 0; i < 2; ++i)
        #pragma unroll
        for (int j = 0; j < 8; ++j) sq[i][j] = 0.f;
    float sa = 0.f;
    #pragma unroll
    for (int qt = 0; qt < 2; ++qt)
        #pragma unroll
        for (int at = 0; at < 8; ++at)
            #pragma unroll
            for (int rr = 0; rr < 4; ++rr) {
                const float e = __expf(acc[qt][at][rr] * 0.125f);
                sv[qt][rr >> 1] += e;
                sq[rr & 1][at]  += e;
                sa += e;
            }

    // --- reductions (split butterflies; validated R4) ---
    sa += __shfl_xor(sa, 16);
    sa += __shfl_xor(sa, 32);
    float tot = sa;
    tot += __shfl_xor(tot, 1);
    tot += __shfl_xor(tot, 2);
    tot += __shfl_xor(tot, 4);
    tot += __shfl_xor(tot, 8);
    const bool b0 = lane & 1;
    const bool b1 = lane & 2;
    float sF;
    {
        float snd0 = b0 ? sv[0][0] : sv[1][0];
        float snd1 = b0 ? sv[0][1] : sv[1][1];
        float r0 = __shfl_xor(snd0, 1);
        float r1 = __shfl_xor(snd1, 1);
        float s0 = (b0 ? sv[1][0] : sv[0][0]) + r0;   // qt = b0, rh = 0
        float s1 = (b0 ? sv[1][1] : sv[0][1]) + r1;   // qt = b0, rh = 1
        float snd = b1 ? s0 : s1;
        float r2 = __shfl_xor(snd, 2);
        sF = (b1 ? s1 : s0) + r2;                     // qt = b0, rh = b1
    }
    sF += __shfl_xor(sF, 4);
    sF += __shfl_xor(sF, 8);
    float s[16];
    #pragma unroll
    for (int i = 0; i < 2; ++i)
        #pragma unroll
        for (int j = 0; j < 8; ++j) s[i * 8 + j] = sq[i][j];
    #pragma unroll
    for (int k = 0; k < 4; ++k) {
        const int d = 1 << k;
        const int m = 16 >> (k + 1);
        const bool b = (lane >> k) & 1;
        #pragma unroll
        for (int x = 0; x < m; ++x) {
            const float snd = b ? s[x] : s[x + m];
            const float rcv = __shfl_xor(snd, d);
            s[x] = (b ? s[x + m] : s[x]) + rcv;
        }
    }
    s[0] += __shfl_xor(s[0], 16);
    s[0] += __shfl_xor(s[0], 32);

    const int g  = h * 512 + vtok * 4 + w;    // softmax group id
    const int b2 = g / 12;
    const int h2 = g - b2 * 12;
    const float invZ = 1.0f / tot;
    const int obase = vtok * DIM + h * HW + w * 16;   // == fetch_o(., g*16+bin)

    if (fm < 4) {                             // 16 writer lanes: v-outputs
        const int quad = lane >> 4;
        const int bin  = (fm & 1) * 8 + quad * 2 + ((fm >> 1) & 1);
        out[(b2 * 16 + bin) * 12 + h2] = sF * invZ * vo[obase + bin];
    }
    if (lane < 16) {                          // 16 writer lanes: q- and a-outputs
        const int qbin = 8 * (lane & 1) + 4 * ((lane >> 1) & 1)
                       + 2 * ((lane >> 2) & 1) + (lane >> 3);
        out[QOUT_OFF + (b2 * 16 + qbin) * 12 + h2] = s[0] * invZ * qo[obase + qbin];
        out[AOUT_OFF + (b2 * 16 + lane) * 12 + h2] = sa   * invZ * ao[obase + lane];
    }
}

extern "C" void kernel_launch(void* const* d_in, const int* in_sizes, int n_in,
                              void* d_out, int out_size, void* d_ws, size_t ws_size,
                              hipStream_t stream)
{
    const float* v   = (const float*)d_in[0];
    const float* q   = (const float*)d_in[1];
    const float* a   = (const float*)d_in[2];
    // d_in[3..5] = masks, unused by the reference forward
    const float* Wv  = (const float*)d_in[6];
    const float* bv  = (const float*)d_in[7];
    const float* Wq  = (const float*)d_in[8];
    const float* bq  = (const float*)d_in[9];
    const float* Wa  = (const float*)d_in[10];
    const float* ba  = (const float*)d_in[11];
    const float* Wvo = (const float*)d_in[12];
    const float* bvo = (const float*)d_in[13];
    const float* Wqo = (const float*)d_in[14];
    const float* bqo = (const float*)d_in[15];
    const float* Wao = (const float*)d_in[16];
    const float* bao = (const float*)d_in[17];

    float* out = (float*)d_out;

    _Float16* Wt  = (_Float16*)d_ws;             // 6 * 589824 f16
    _Float16* vI  = Wt + 6 * WELEMS;
    _Float16* qI  = vI + PROJ_ELEMS;
    _Float16* aI  = qI + PROJ_ELEMS;
    _Float16* vpH = aI + PROJ_ELEMS;
    _Float16* qpH = vpH + PROJ_ELEMS;
    _Float16* apH = qpH + PROJ_ELEMS;
    float*    vo  = (float*)(apH + PROJ_ELEMS);
    float*    qo  = vo + PROJ_ELEMS;
    float*    ao  = qo + PROJ_ELEMS;

    // 1) transpose+convert weights to f16 [n][k]; convert inputs to f16
    prep_kernel<<<dim3(12, 12, 7), 256, 0, stream>>>(
        v, q, a, Wv, Wq, Wa, Wvo, Wqo, Wao, Wt, vI, qI, aI);
    // 2) stage-1 projections (f16 out)
    proj_kernel<<<dim3(8, 48, 3), 64, 0, stream>>>(
        vI, qI, aI, Wt, Wt + WELEMS, Wt + 2 * WELEMS,
        bv, bq, ba, vpH, qpH, apH, 1);
    // 3) stage-2 projections (f32 out)
    proj_kernel<<<dim3(8, 48, 3), 64, 0, stream>>>(
        vpH, qpH, apH, Wt + 3 * WELEMS, Wt + 4 * WELEMS, Wt + 5 * WELEMS,
        bvo, bqo, bao, vo, qo, ao, 0);
    // 4) fused trilinear scores + grouped softmax + marginal outputs
    fused_attn_kernel<<<dim3(SEQ, NH), 256, 0, stream>>>(
        vpH, qpH, apH, vo, qo, ao, out);
}